// Round 1
// 408.316 us; speedup vs baseline: 1.0132x; 1.0132x over previous
//
#include <hip/hip_runtime.h>
#include <hip/hip_bf16.h>

#define BATCH 32
#define CDIM  256
#define TDIM  4096

using short8  = __attribute__((ext_vector_type(8))) short;
using floatx4 = __attribute__((ext_vector_type(4))) float;

// RNE float -> bf16 (finite inputs)
__device__ __forceinline__ unsigned f2bf(float f) {
  unsigned u = __float_as_uint(f);
  return (u + 0x7fffu + ((u >> 16) & 1u)) >> 16;
}
__device__ __forceinline__ unsigned cvt_pk_bf16(float a, float b) {
  return f2bf(a) | (f2bf(b) << 16);
}
__device__ __forceinline__ float bf_lo(unsigned u) { return __uint_as_float(u << 16); }
__device__ __forceinline__ float bf_hi(unsigned u) { return __uint_as_float(u & 0xffff0000u); }

// ---------------------------------------------------------------------------
// Kernel 1: per-batch Gram with split-bf16.
//   E1 = h·h^T, E2 = l·h^T   (energy[i,j] = E1[i,j] + E2[i,j] + E2[j,i])
// Tile: 128(I) x 64(J), K = 4096, BK = 64. Grid = 32 b * 2 it * 4 jt = 256.
// 512 threads = 8 waves in 4x2, wave tile 32x32 (2x2 of 16x16x32 MFMA).
// LDS rows are 64 shorts (128 B); 16B granules XOR-swizzled by (row&7) so
// both ds_write_b128 and ds_read_b128 hit every bank exactly 8x (minimum).
// ---------------------------------------------------------------------------
__global__ __launch_bounds__(512, 1)
void gram_kernel(const float* __restrict__ x,
                 float* __restrict__ E1, float* __restrict__ E2) {
  __shared__ __align__(16) short hI[128 * 64];
  __shared__ __align__(16) short lI[128 * 64];
  __shared__ __align__(16) short hJ[64 * 64];

  const int tid = threadIdx.x;
  const int bx  = blockIdx.x;

  // XCD swizzle: slot s = bx&7 hosts batches {s, s+8, s+16, s+24}; a batch's
  // 8 tile-jobs land on one XCD so shared panels reuse that XCD's L2.
  const int s   = bx & 7;
  const int seq = bx >> 3;
  const int b   = s + ((seq >> 3) << 3);
  const int job = seq & 7;
  const int i0  = (job >> 2) << 7;   // 0 / 128
  const int j0  = (job & 3) << 6;    // 0 / 64 / 128 / 192

  const float* xb = x + ((size_t)b << 20);   // b * 256 * 4096

  // staging map:
  //  tid 0..255  : I panel, row = tid>>1 (128 rows), half = tid&1, 32 floats
  //  tid 256..511: J panel, row = (tid&255)>>2 (64 rows), q = tid&3, 16 floats
  const bool isJ   = tid >= 256;
  const int  irow  = tid >> 1;
  const int  ihalf = tid & 1;
  const int  jrow  = (tid & 255) >> 2;
  const int  jq    = tid & 3;

  const float* pS = isJ
      ? xb + (size_t)(j0 + jrow) * TDIM + (jq << 4)
      : xb + (size_t)(i0 + irow) * TDIM + (ihalf << 5);

  floatx4 acc1[2][2], acc2[2][2];
#pragma unroll
  for (int m = 0; m < 2; ++m)
#pragma unroll
    for (int n = 0; n < 2; ++n) {
      acc1[m][n] = {0.f, 0.f, 0.f, 0.f};
      acc2[m][n] = {0.f, 0.f, 0.f, 0.f};
    }

  const int lane = tid & 63;
  const int w    = tid >> 6;
  const int wib  = (w >> 1) << 5;   // 0/32/64/96
  const int wjb  = (w & 1) << 5;    // 0/32
  const int fr   = lane & 15;
  const int q    = lane >> 4;
  const int f7   = fr & 7;

  // fragment read offsets (shorts): row*64 + ((granule ^ (row&7)) * 8)
  const int g0 = ((q)     ^ f7) << 3;   // k-step 0, granule q
  const int g1 = ((q + 4) ^ f7) << 3;   // k-step 1, granule 4+q
  const int a0 = (wib + fr) << 6;
  const int a1 = (wib + 16 + fr) << 6;
  const int b0 = (wjb + fr) << 6;
  const int b1 = (wjb + 16 + fr) << 6;

  // prefetch step 0 (I: 32 floats, J: 16 floats)
  float4 r0, r1, r2, r3, r4, r5, r6, r7;
  r0 = ((const float4*)pS)[0]; r1 = ((const float4*)pS)[1];
  r2 = ((const float4*)pS)[2]; r3 = ((const float4*)pS)[3];
  if (!isJ) {
    r4 = ((const float4*)pS)[4]; r5 = ((const float4*)pS)[5];
    r6 = ((const float4*)pS)[6]; r7 = ((const float4*)pS)[7];
  }

  for (int ks = 0; ks < TDIM / 64; ++ks) {
    // convert current regs (h = bf16 RNE, l = bf16(x - h))
    unsigned h0 = cvt_pk_bf16(r0.x, r0.y), h1 = cvt_pk_bf16(r0.z, r0.w);
    unsigned h2 = cvt_pk_bf16(r1.x, r1.y), h3 = cvt_pk_bf16(r1.z, r1.w);
    unsigned h4 = cvt_pk_bf16(r2.x, r2.y), h5 = cvt_pk_bf16(r2.z, r2.w);
    unsigned h6 = cvt_pk_bf16(r3.x, r3.y), h7 = cvt_pk_bf16(r3.z, r3.w);
    unsigned h8, h9, hA, hB, hC, hD, hE, hF;
    unsigned l0, l1, l2, l3, l4, l5, l6, l7, l8, l9, lA, lB, lC, lD, lE, lF;
    if (!isJ) {
      h8 = cvt_pk_bf16(r4.x, r4.y); h9 = cvt_pk_bf16(r4.z, r4.w);
      hA = cvt_pk_bf16(r5.x, r5.y); hB = cvt_pk_bf16(r5.z, r5.w);
      hC = cvt_pk_bf16(r6.x, r6.y); hD = cvt_pk_bf16(r6.z, r6.w);
      hE = cvt_pk_bf16(r7.x, r7.y); hF = cvt_pk_bf16(r7.z, r7.w);
      l0 = cvt_pk_bf16(r0.x - bf_lo(h0), r0.y - bf_hi(h0));
      l1 = cvt_pk_bf16(r0.z - bf_lo(h1), r0.w - bf_hi(h1));
      l2 = cvt_pk_bf16(r1.x - bf_lo(h2), r1.y - bf_hi(h2));
      l3 = cvt_pk_bf16(r1.z - bf_lo(h3), r1.w - bf_hi(h3));
      l4 = cvt_pk_bf16(r2.x - bf_lo(h4), r2.y - bf_hi(h4));
      l5 = cvt_pk_bf16(r2.z - bf_lo(h5), r2.w - bf_hi(h5));
      l6 = cvt_pk_bf16(r3.x - bf_lo(h6), r3.y - bf_hi(h6));
      l7 = cvt_pk_bf16(r3.z - bf_lo(h7), r3.w - bf_hi(h7));
      l8 = cvt_pk_bf16(r4.x - bf_lo(h8), r4.y - bf_hi(h8));
      l9 = cvt_pk_bf16(r4.z - bf_lo(h9), r4.w - bf_hi(h9));
      lA = cvt_pk_bf16(r5.x - bf_lo(hA), r5.y - bf_hi(hA));
      lB = cvt_pk_bf16(r5.z - bf_lo(hB), r5.w - bf_hi(hB));
      lC = cvt_pk_bf16(r6.x - bf_lo(hC), r6.y - bf_hi(hC));
      lD = cvt_pk_bf16(r6.z - bf_lo(hD), r6.w - bf_hi(hD));
      lE = cvt_pk_bf16(r7.x - bf_lo(hE), r7.y - bf_hi(hE));
      lF = cvt_pk_bf16(r7.z - bf_lo(hF), r7.w - bf_hi(hF));
    }

    __syncthreads();   // previous iteration's LDS reads done
    if (!isJ) {
      const int rb = irow << 6;
      const int s7 = irow & 7;
      const int gb = ihalf << 2;
      *(uint4*)&hI[rb + (((gb + 0) ^ s7) << 3)] = make_uint4(h0, h1, h2, h3);
      *(uint4*)&hI[rb + (((gb + 1) ^ s7) << 3)] = make_uint4(h4, h5, h6, h7);
      *(uint4*)&hI[rb + (((gb + 2) ^ s7) << 3)] = make_uint4(h8, h9, hA, hB);
      *(uint4*)&hI[rb + (((gb + 3) ^ s7) << 3)] = make_uint4(hC, hD, hE, hF);
      *(uint4*)&lI[rb + (((gb + 0) ^ s7) << 3)] = make_uint4(l0, l1, l2, l3);
      *(uint4*)&lI[rb + (((gb + 1) ^ s7) << 3)] = make_uint4(l4, l5, l6, l7);
      *(uint4*)&lI[rb + (((gb + 2) ^ s7) << 3)] = make_uint4(l8, l9, lA, lB);
      *(uint4*)&lI[rb + (((gb + 3) ^ s7) << 3)] = make_uint4(lC, lD, lE, lF);
    } else {
      const int rb = jrow << 6;
      const int s7 = jrow & 7;
      const int gb = jq << 1;
      *(uint4*)&hJ[rb + (((gb + 0) ^ s7) << 3)] = make_uint4(h0, h1, h2, h3);
      *(uint4*)&hJ[rb + (((gb + 1) ^ s7) << 3)] = make_uint4(h4, h5, h6, h7);
    }
    __syncthreads();

    if (ks < TDIM / 64 - 1) {
      pS += 64;
      r0 = ((const float4*)pS)[0]; r1 = ((const float4*)pS)[1];
      r2 = ((const float4*)pS)[2]; r3 = ((const float4*)pS)[3];
      if (!isJ) {
        r4 = ((const float4*)pS)[4]; r5 = ((const float4*)pS)[5];
        r6 = ((const float4*)pS)[6]; r7 = ((const float4*)pS)[7];
      }
    }

    // k-step 0
    {
      short8 Ah0 = *(const short8*)&hI[a0 + g0];
      short8 Ah1 = *(const short8*)&hI[a1 + g0];
      short8 Al0 = *(const short8*)&lI[a0 + g0];
      short8 Al1 = *(const short8*)&lI[a1 + g0];
      short8 Bh0 = *(const short8*)&hJ[b0 + g0];
      short8 Bh1 = *(const short8*)&hJ[b1 + g0];
      acc1[0][0] = __builtin_amdgcn_mfma_f32_16x16x32_bf16(Ah0, Bh0, acc1[0][0], 0, 0, 0);
      acc1[0][1] = __builtin_amdgcn_mfma_f32_16x16x32_bf16(Ah0, Bh1, acc1[0][1], 0, 0, 0);
      acc1[1][0] = __builtin_amdgcn_mfma_f32_16x16x32_bf16(Ah1, Bh0, acc1[1][0], 0, 0, 0);
      acc1[1][1] = __builtin_amdgcn_mfma_f32_16x16x32_bf16(Ah1, Bh1, acc1[1][1], 0, 0, 0);
      acc2[0][0] = __builtin_amdgcn_mfma_f32_16x16x32_bf16(Al0, Bh0, acc2[0][0], 0, 0, 0);
      acc2[0][1] = __builtin_amdgcn_mfma_f32_16x16x32_bf16(Al0, Bh1, acc2[0][1], 0, 0, 0);
      acc2[1][0] = __builtin_amdgcn_mfma_f32_16x16x32_bf16(Al1, Bh0, acc2[1][0], 0, 0, 0);
      acc2[1][1] = __builtin_amdgcn_mfma_f32_16x16x32_bf16(Al1, Bh1, acc2[1][1], 0, 0, 0);
    }
    // k-step 1
    {
      short8 Ah0 = *(const short8*)&hI[a0 + g1];
      short8 Ah1 = *(const short8*)&hI[a1 + g1];
      short8 Al0 = *(const short8*)&lI[a0 + g1];
      short8 Al1 = *(const short8*)&lI[a1 + g1];
      short8 Bh0 = *(const short8*)&hJ[b0 + g1];
      short8 Bh1 = *(const short8*)&hJ[b1 + g1];
      acc1[0][0] = __builtin_amdgcn_mfma_f32_16x16x32_bf16(Ah0, Bh0, acc1[0][0], 0, 0, 0);
      acc1[0][1] = __builtin_amdgcn_mfma_f32_16x16x32_bf16(Ah0, Bh1, acc1[0][1], 0, 0, 0);
      acc1[1][0] = __builtin_amdgcn_mfma_f32_16x16x32_bf16(Ah1, Bh0, acc1[1][0], 0, 0, 0);
      acc1[1][1] = __builtin_amdgcn_mfma_f32_16x16x32_bf16(Ah1, Bh1, acc1[1][1], 0, 0, 0);
      acc2[0][0] = __builtin_amdgcn_mfma_f32_16x16x32_bf16(Al0, Bh0, acc2[0][0], 0, 0, 0);
      acc2[0][1] = __builtin_amdgcn_mfma_f32_16x16x32_bf16(Al0, Bh1, acc2[0][1], 0, 0, 0);
      acc2[1][0] = __builtin_amdgcn_mfma_f32_16x16x32_bf16(Al1, Bh0, acc2[1][0], 0, 0, 0);
      acc2[1][1] = __builtin_amdgcn_mfma_f32_16x16x32_bf16(Al1, Bh1, acc2[1][1], 0, 0, 0);
    }
  }

  // epilogue: C/D layout col = lane&15, row = (lane>>4)*4 + reg
#pragma unroll
  for (int m = 0; m < 2; ++m)
#pragma unroll
    for (int n = 0; n < 2; ++n) {
      const int gr = i0 + wib + 16 * m + 4 * q;
      const int gc = j0 + wjb + 16 * n + fr;
      size_t base = (((size_t)b * CDIM + gr) << 8) + gc;
#pragma unroll
      for (int r = 0; r < 4; ++r) {
        E1[base + ((size_t)r << 8)] = acc1[m][n][r];
        E2[base + ((size_t)r << 8)] = acc2[m][n][r];
      }
    }
}

// ---------------------------------------------------------------------------
// Kernel 2: softmax over rows of energy = E1 + E2 + E2^T, att = softmax(-e)
// Block = (b, 32-row group); all global reads coalesced; the E2 transpose is
// materialized through LDS (stride-33 pad). grid 256 x 256 threads.
// ---------------------------------------------------------------------------
__global__ __launch_bounds__(256)
void softmax_kernel(const float* __restrict__ E1, const float* __restrict__ E2,
                    __hip_bfloat16* __restrict__ att) {
  __shared__ float SR[32][264];   // E1+E2 rows i0..i0+31
  __shared__ float ST[256][33];   // E2 columns i0..i0+31 (transposed slab)

  const int tid = threadIdx.x;
  const int b   = blockIdx.x >> 3;
  const int i0  = (blockIdx.x & 7) << 5;
  const size_t base = (size_t)b << 16;

  {  // rows: 32 x 256, 8 threads per row, 32 floats each
    const int r  = tid >> 3;
    const int c0 = (tid & 7) << 5;
    const float* p1 = E1 + base + ((size_t)(i0 + r) << 8) + c0;
    const float* p2 = E2 + base + ((size_t)(i0 + r) << 8) + c0;
#pragma unroll
    for (int u = 0; u < 32; u += 4) {
      float4 a = *(const float4*)(p1 + u);
      float4 c = *(const float4*)(p2 + u);
      *(float4*)&SR[r][c0 + u] = make_float4(a.x + c.x, a.y + c.y, a.z + c.z, a.w + c.w);
    }
  }
  {  // cols: lane c reads column i0+c down 32 rows (coalesced across lanes)
    const int c  = tid & 31;
    const int j0 = (tid >> 5) << 5;
    const float* p = E2 + base + i0 + c;
#pragma unroll
    for (int jj = 0; jj < 32; ++jj)
      ST[j0 + jj][c] = p[(size_t)(j0 + jj) << 8];
  }
  __syncthreads();

  const int r  = tid >> 3;
  const int t7 = tid & 7;
  float z[32];
  float m = -3.4e38f;
#pragma unroll
  for (int k = 0; k < 32; ++k) {
    const int j = t7 + (k << 3);
    const float e = SR[r][j] + ST[j][r];
    z[k] = -e;
    m = fmaxf(m, z[k]);
  }
  m = fmaxf(m, __shfl_xor(m, 1, 64));
  m = fmaxf(m, __shfl_xor(m, 2, 64));
  m = fmaxf(m, __shfl_xor(m, 4, 64));
  float ssum = 0.f;
#pragma unroll
  for (int k = 0; k < 32; ++k) { z[k] = expf(z[k] - m); ssum += z[k]; }
  ssum += __shfl_xor(ssum, 1, 64);
  ssum += __shfl_xor(ssum, 2, 64);
  ssum += __shfl_xor(ssum, 4, 64);
  const float inv = 1.f / ssum;

  unsigned short* arow = (unsigned short*)att + base + ((size_t)(i0 + r) << 8);
#pragma unroll
  for (int k = 0; k < 32; ++k) {
    const int j = t7 + (k << 3);
    arow[j] = (unsigned short)f2bf(z[k] * inv);
  }
}

// ---------------------------------------------------------------------------
// Kernel 3: out = gamma * (att @ x) + x   (unchanged this round)
// Tile 128(M) x 128(N), K = 256, BK = 32. Grid = 32 * 2 * 32 = 2048.
// ---------------------------------------------------------------------------
__global__ __launch_bounds__(256, 2)
void pv_kernel(const float* __restrict__ x, const __hip_bfloat16* __restrict__ att,
               const float* __restrict__ gamma, float* __restrict__ out) {
  __shared__ __align__(16) short As[128 * 40];   // att rows [i][j], j-contig
  __shared__ __align__(16) short Bt[128 * 40];   // x tile transposed: [t][k]

  const int tid = threadIdx.x;
  const int bx  = blockIdx.x;
  const int b   = bx >> 6;
  const int i0  = ((bx >> 5) & 1) << 7;  // 0 / 128
  const int t0  = (bx & 31) << 7;        // n-tile * 128

  const float* xb = x + ((size_t)b << 20);
  const unsigned short* attb = (const unsigned short*)att + ((size_t)b << 16);

  const int arow = tid >> 1;
  const int aoff = (tid & 1) << 4;
  const int kg = tid >> 5;
  const int tg = tid & 31;

  floatx4 acc[4][4];
#pragma unroll
  for (int m = 0; m < 4; ++m)
#pragma unroll
    for (int n = 0; n < 4; ++n) acc[m][n] = {0.f, 0.f, 0.f, 0.f};

  const int lane = tid & 63;
  const int w    = tid >> 6;
  const int wm   = (w >> 1) << 6;  // 0 / 64
  const int wn   = (w & 1) << 6;
  const int fr   = lane & 15;
  const int q    = lane >> 4;

  const unsigned short* pA = attb + (size_t)(i0 + arow) * CDIM + aoff;
  const float* pB = xb + (size_t)(kg * 4) * TDIM + t0 + tg;

  uint4 ra0 = *(const uint4*)pA;
  uint4 ra1 = *(const uint4*)(pA + 8);
  float xv[4][4];
#pragma unroll
  for (int kk = 0; kk < 4; ++kk)
#pragma unroll
    for (int tt = 0; tt < 4; ++tt) xv[kk][tt] = pB[kk * TDIM + tt * 32];

  for (int ks = 0; ks < CDIM / 32; ++ks) {
    unsigned bu[4][2];
#pragma unroll
    for (int tt = 0; tt < 4; ++tt) {
      bu[tt][0] = cvt_pk_bf16(xv[0][tt], xv[1][tt]);
      bu[tt][1] = cvt_pk_bf16(xv[2][tt], xv[3][tt]);
    }

    __syncthreads();
    *(uint4*)(&As[arow * 40 + aoff])     = ra0;
    *(uint4*)(&As[arow * 40 + aoff + 8]) = ra1;
#pragma unroll
    for (int tt = 0; tt < 4; ++tt)
      *(uint2*)(&Bt[(tg + tt * 32) * 40 + kg * 4]) = make_uint2(bu[tt][0], bu[tt][1]);
    __syncthreads();

    if (ks < CDIM / 32 - 1) {
      pA += 32; pB += (size_t)32 * TDIM;
      ra0 = *(const uint4*)pA;
      ra1 = *(const uint4*)(pA + 8);
#pragma unroll
      for (int kk = 0; kk < 4; ++kk)
#pragma unroll
        for (int tt = 0; tt < 4; ++tt) xv[kk][tt] = pB[kk * TDIM + tt * 32];
    }

    short8 Af[4], Bf[4];
#pragma unroll
    for (int m = 0; m < 4; ++m) Af[m] = *(const short8*)(&As[(wm + 16 * m + fr) * 40 + q * 8]);
#pragma unroll
    for (int n = 0; n < 4; ++n) Bf[n] = *(const short8*)(&Bt[(wn + 16 * n + fr) * 40 + q * 8]);
#pragma unroll
    for (int m = 0; m < 4; ++m)
#pragma unroll
      for (int n = 0; n < 4; ++n)
        acc[m][n] = __builtin_amdgcn_mfma_f32_16x16x32_bf16(Af[m], Bf[n], acc[m][n], 0, 0, 0);
  }

  const float g = gamma[0];
#pragma unroll
  for (int m = 0; m < 4; ++m)
#pragma unroll
    for (int n = 0; n < 4; ++n) {
      const int gr = i0 + wm + 16 * m + 4 * q;
      const int gc = t0 + wn + 16 * n + fr;
      size_t base = ((size_t)b << 20) + (size_t)gr * TDIM + gc;
#pragma unroll
      for (int r = 0; r < 4; ++r) {
        size_t idx = base + (size_t)r * TDIM;
        out[idx] = g * acc[m][n][r] + x[idx];
      }
    }
}

// ---------------------------------------------------------------------------
extern "C" void kernel_launch(void* const* d_in, const int* in_sizes, int n_in,
                              void* d_out, int out_size, void* d_ws, size_t ws_size,
                              hipStream_t stream) {
  (void)in_sizes; (void)n_in; (void)out_size; (void)ws_size;
  const float* x     = (const float*)d_in[0];
  const float* gamma = (const float*)d_in[1];
  float* out = (float*)d_out;

  const size_t EN = (size_t)BATCH * CDIM * CDIM;  // 2,097,152
  float* E1 = (float*)d_ws;
  float* E2 = E1 + EN;
  __hip_bfloat16* att = (__hip_bfloat16*)(E2 + EN);
  // ws usage: 8 MiB + 8 MiB + 4 MiB = 20 MiB (unchanged)

  gram_kernel<<<dim3(256), dim3(512), 0, stream>>>(x, E1, E2);
  softmax_kernel<<<dim3(BATCH * 8), dim3(256), 0, stream>>>(E1, E2, att);
  pv_kernel<<<dim3(2048), dim3(256), 0, stream>>>(x, att, gamma, out);
}

// Round 2
// 400.019 us; speedup vs baseline: 1.0342x; 1.0207x over previous
//
#include <hip/hip_runtime.h>
#include <hip/hip_bf16.h>

#define BATCH 32
#define CDIM  256
#define TDIM  4096

using short8  = __attribute__((ext_vector_type(8))) short;
using floatx4 = __attribute__((ext_vector_type(4))) float;

// RNE float -> bf16 (finite inputs)
__device__ __forceinline__ unsigned f2bf(float f) {
  unsigned u = __float_as_uint(f);
  return (u + 0x7fffu + ((u >> 16) & 1u)) >> 16;
}
__device__ __forceinline__ unsigned cvt_pk_bf16(float a, float b) {
  return f2bf(a) | (f2bf(b) << 16);
}
__device__ __forceinline__ float bf_lo(unsigned u) { return __uint_as_float(u << 16); }
__device__ __forceinline__ float bf_hi(unsigned u) { return __uint_as_float(u & 0xffff0000u); }

// ---------------------------------------------------------------------------
// Kernel 1: per-batch Gram with split-bf16.  (unchanged this round)
//   E1 = h·h^T, E2 = l·h^T   (energy[i,j] = E1[i,j] + E2[i,j] + E2[j,i])
// Tile: 128(I) x 64(J), K = 4096, BK = 64. Grid = 32 b * 2 it * 4 jt = 256.
// ---------------------------------------------------------------------------
__global__ __launch_bounds__(512, 1)
void gram_kernel(const float* __restrict__ x,
                 float* __restrict__ E1, float* __restrict__ E2) {
  __shared__ __align__(16) short hI[128 * 64];
  __shared__ __align__(16) short lI[128 * 64];
  __shared__ __align__(16) short hJ[64 * 64];

  const int tid = threadIdx.x;
  const int bx  = blockIdx.x;

  const int s   = bx & 7;
  const int seq = bx >> 3;
  const int b   = s + ((seq >> 3) << 3);
  const int job = seq & 7;
  const int i0  = (job >> 2) << 7;   // 0 / 128
  const int j0  = (job & 3) << 6;    // 0 / 64 / 128 / 192

  const float* xb = x + ((size_t)b << 20);   // b * 256 * 4096

  const bool isJ   = tid >= 256;
  const int  irow  = tid >> 1;
  const int  ihalf = tid & 1;
  const int  jrow  = (tid & 255) >> 2;
  const int  jq    = tid & 3;

  const float* pS = isJ
      ? xb + (size_t)(j0 + jrow) * TDIM + (jq << 4)
      : xb + (size_t)(i0 + irow) * TDIM + (ihalf << 5);

  floatx4 acc1[2][2], acc2[2][2];
#pragma unroll
  for (int m = 0; m < 2; ++m)
#pragma unroll
    for (int n = 0; n < 2; ++n) {
      acc1[m][n] = {0.f, 0.f, 0.f, 0.f};
      acc2[m][n] = {0.f, 0.f, 0.f, 0.f};
    }

  const int lane = tid & 63;
  const int w    = tid >> 6;
  const int wib  = (w >> 1) << 5;   // 0/32/64/96
  const int wjb  = (w & 1) << 5;    // 0/32
  const int fr   = lane & 15;
  const int q    = lane >> 4;
  const int f7   = fr & 7;

  const int g0 = ((q)     ^ f7) << 3;
  const int g1 = ((q + 4) ^ f7) << 3;
  const int a0 = (wib + fr) << 6;
  const int a1 = (wib + 16 + fr) << 6;
  const int b0 = (wjb + fr) << 6;
  const int b1 = (wjb + 16 + fr) << 6;

  float4 r0, r1, r2, r3, r4, r5, r6, r7;
  r0 = ((const float4*)pS)[0]; r1 = ((const float4*)pS)[1];
  r2 = ((const float4*)pS)[2]; r3 = ((const float4*)pS)[3];
  if (!isJ) {
    r4 = ((const float4*)pS)[4]; r5 = ((const float4*)pS)[5];
    r6 = ((const float4*)pS)[6]; r7 = ((const float4*)pS)[7];
  }

  for (int ks = 0; ks < TDIM / 64; ++ks) {
    unsigned h0 = cvt_pk_bf16(r0.x, r0.y), h1 = cvt_pk_bf16(r0.z, r0.w);
    unsigned h2 = cvt_pk_bf16(r1.x, r1.y), h3 = cvt_pk_bf16(r1.z, r1.w);
    unsigned h4 = cvt_pk_bf16(r2.x, r2.y), h5 = cvt_pk_bf16(r2.z, r2.w);
    unsigned h6 = cvt_pk_bf16(r3.x, r3.y), h7 = cvt_pk_bf16(r3.z, r3.w);
    unsigned h8, h9, hA, hB, hC, hD, hE, hF;
    unsigned l0, l1, l2, l3, l4, l5, l6, l7, l8, l9, lA, lB, lC, lD, lE, lF;
    if (!isJ) {
      h8 = cvt_pk_bf16(r4.x, r4.y); h9 = cvt_pk_bf16(r4.z, r4.w);
      hA = cvt_pk_bf16(r5.x, r5.y); hB = cvt_pk_bf16(r5.z, r5.w);
      hC = cvt_pk_bf16(r6.x, r6.y); hD = cvt_pk_bf16(r6.z, r6.w);
      hE = cvt_pk_bf16(r7.x, r7.y); hF = cvt_pk_bf16(r7.z, r7.w);
      l0 = cvt_pk_bf16(r0.x - bf_lo(h0), r0.y - bf_hi(h0));
      l1 = cvt_pk_bf16(r0.z - bf_lo(h1), r0.w - bf_hi(h1));
      l2 = cvt_pk_bf16(r1.x - bf_lo(h2), r1.y - bf_hi(h2));
      l3 = cvt_pk_bf16(r1.z - bf_lo(h3), r1.w - bf_hi(h3));
      l4 = cvt_pk_bf16(r2.x - bf_lo(h4), r2.y - bf_hi(h4));
      l5 = cvt_pk_bf16(r2.z - bf_lo(h5), r2.w - bf_hi(h5));
      l6 = cvt_pk_bf16(r3.x - bf_lo(h6), r3.y - bf_hi(h6));
      l7 = cvt_pk_bf16(r3.z - bf_lo(h7), r3.w - bf_hi(h7));
      l8 = cvt_pk_bf16(r4.x - bf_lo(h8), r4.y - bf_hi(h8));
      l9 = cvt_pk_bf16(r4.z - bf_lo(h9), r4.w - bf_hi(h9));
      lA = cvt_pk_bf16(r5.x - bf_lo(hA), r5.y - bf_hi(hA));
      lB = cvt_pk_bf16(r5.z - bf_lo(hB), r5.w - bf_hi(hB));
      lC = cvt_pk_bf16(r6.x - bf_lo(hC), r6.y - bf_hi(hC));
      lD = cvt_pk_bf16(r6.z - bf_lo(hD), r6.w - bf_hi(hD));
      lE = cvt_pk_bf16(r7.x - bf_lo(hE), r7.y - bf_hi(hE));
      lF = cvt_pk_bf16(r7.z - bf_lo(hF), r7.w - bf_hi(hF));
    }

    __syncthreads();
    if (!isJ) {
      const int rb = irow << 6;
      const int s7 = irow & 7;
      const int gb = ihalf << 2;
      *(uint4*)&hI[rb + (((gb + 0) ^ s7) << 3)] = make_uint4(h0, h1, h2, h3);
      *(uint4*)&hI[rb + (((gb + 1) ^ s7) << 3)] = make_uint4(h4, h5, h6, h7);
      *(uint4*)&hI[rb + (((gb + 2) ^ s7) << 3)] = make_uint4(h8, h9, hA, hB);
      *(uint4*)&hI[rb + (((gb + 3) ^ s7) << 3)] = make_uint4(hC, hD, hE, hF);
      *(uint4*)&lI[rb + (((gb + 0) ^ s7) << 3)] = make_uint4(l0, l1, l2, l3);
      *(uint4*)&lI[rb + (((gb + 1) ^ s7) << 3)] = make_uint4(l4, l5, l6, l7);
      *(uint4*)&lI[rb + (((gb + 2) ^ s7) << 3)] = make_uint4(l8, l9, lA, lB);
      *(uint4*)&lI[rb + (((gb + 3) ^ s7) << 3)] = make_uint4(lC, lD, lE, lF);
    } else {
      const int rb = jrow << 6;
      const int s7 = jrow & 7;
      const int gb = jq << 1;
      *(uint4*)&hJ[rb + (((gb + 0) ^ s7) << 3)] = make_uint4(h0, h1, h2, h3);
      *(uint4*)&hJ[rb + (((gb + 1) ^ s7) << 3)] = make_uint4(h4, h5, h6, h7);
    }
    __syncthreads();

    if (ks < TDIM / 64 - 1) {
      pS += 64;
      r0 = ((const float4*)pS)[0]; r1 = ((const float4*)pS)[1];
      r2 = ((const float4*)pS)[2]; r3 = ((const float4*)pS)[3];
      if (!isJ) {
        r4 = ((const float4*)pS)[4]; r5 = ((const float4*)pS)[5];
        r6 = ((const float4*)pS)[6]; r7 = ((const float4*)pS)[7];
      }
    }

    {
      short8 Ah0 = *(const short8*)&hI[a0 + g0];
      short8 Ah1 = *(const short8*)&hI[a1 + g0];
      short8 Al0 = *(const short8*)&lI[a0 + g0];
      short8 Al1 = *(const short8*)&lI[a1 + g0];
      short8 Bh0 = *(const short8*)&hJ[b0 + g0];
      short8 Bh1 = *(const short8*)&hJ[b1 + g0];
      acc1[0][0] = __builtin_amdgcn_mfma_f32_16x16x32_bf16(Ah0, Bh0, acc1[0][0], 0, 0, 0);
      acc1[0][1] = __builtin_amdgcn_mfma_f32_16x16x32_bf16(Ah0, Bh1, acc1[0][1], 0, 0, 0);
      acc1[1][0] = __builtin_amdgcn_mfma_f32_16x16x32_bf16(Ah1, Bh0, acc1[1][0], 0, 0, 0);
      acc1[1][1] = __builtin_amdgcn_mfma_f32_16x16x32_bf16(Ah1, Bh1, acc1[1][1], 0, 0, 0);
      acc2[0][0] = __builtin_amdgcn_mfma_f32_16x16x32_bf16(Al0, Bh0, acc2[0][0], 0, 0, 0);
      acc2[0][1] = __builtin_amdgcn_mfma_f32_16x16x32_bf16(Al0, Bh1, acc2[0][1], 0, 0, 0);
      acc2[1][0] = __builtin_amdgcn_mfma_f32_16x16x32_bf16(Al1, Bh0, acc2[1][0], 0, 0, 0);
      acc2[1][1] = __builtin_amdgcn_mfma_f32_16x16x32_bf16(Al1, Bh1, acc2[1][1], 0, 0, 0);
    }
    {
      short8 Ah0 = *(const short8*)&hI[a0 + g1];
      short8 Ah1 = *(const short8*)&hI[a1 + g1];
      short8 Al0 = *(const short8*)&lI[a0 + g1];
      short8 Al1 = *(const short8*)&lI[a1 + g1];
      short8 Bh0 = *(const short8*)&hJ[b0 + g1];
      short8 Bh1 = *(const short8*)&hJ[b1 + g1];
      acc1[0][0] = __builtin_amdgcn_mfma_f32_16x16x32_bf16(Ah0, Bh0, acc1[0][0], 0, 0, 0);
      acc1[0][1] = __builtin_amdgcn_mfma_f32_16x16x32_bf16(Ah0, Bh1, acc1[0][1], 0, 0, 0);
      acc1[1][0] = __builtin_amdgcn_mfma_f32_16x16x32_bf16(Ah1, Bh0, acc1[1][0], 0, 0, 0);
      acc1[1][1] = __builtin_amdgcn_mfma_f32_16x16x32_bf16(Ah1, Bh1, acc1[1][1], 0, 0, 0);
      acc2[0][0] = __builtin_amdgcn_mfma_f32_16x16x32_bf16(Al0, Bh0, acc2[0][0], 0, 0, 0);
      acc2[0][1] = __builtin_amdgcn_mfma_f32_16x16x32_bf16(Al0, Bh1, acc2[0][1], 0, 0, 0);
      acc2[1][0] = __builtin_amdgcn_mfma_f32_16x16x32_bf16(Al1, Bh0, acc2[1][0], 0, 0, 0);
      acc2[1][1] = __builtin_amdgcn_mfma_f32_16x16x32_bf16(Al1, Bh1, acc2[1][1], 0, 0, 0);
    }
  }

#pragma unroll
  for (int m = 0; m < 2; ++m)
#pragma unroll
    for (int n = 0; n < 2; ++n) {
      const int gr = i0 + wib + 16 * m + 4 * q;
      const int gc = j0 + wjb + 16 * n + fr;
      size_t base = (((size_t)b * CDIM + gr) << 8) + gc;
#pragma unroll
      for (int r = 0; r < 4; ++r) {
        E1[base + ((size_t)r << 8)] = acc1[m][n][r];
        E2[base + ((size_t)r << 8)] = acc2[m][n][r];
      }
    }
}

// ---------------------------------------------------------------------------
// Kernel 2: softmax (unchanged this round)
// ---------------------------------------------------------------------------
__global__ __launch_bounds__(256)
void softmax_kernel(const float* __restrict__ E1, const float* __restrict__ E2,
                    __hip_bfloat16* __restrict__ att) {
  __shared__ float SR[32][264];
  __shared__ float ST[256][33];

  const int tid = threadIdx.x;
  const int b   = blockIdx.x >> 3;
  const int i0  = (blockIdx.x & 7) << 5;
  const size_t base = (size_t)b << 16;

  {
    const int r  = tid >> 3;
    const int c0 = (tid & 7) << 5;
    const float* p1 = E1 + base + ((size_t)(i0 + r) << 8) + c0;
    const float* p2 = E2 + base + ((size_t)(i0 + r) << 8) + c0;
#pragma unroll
    for (int u = 0; u < 32; u += 4) {
      float4 a = *(const float4*)(p1 + u);
      float4 c = *(const float4*)(p2 + u);
      *(float4*)&SR[r][c0 + u] = make_float4(a.x + c.x, a.y + c.y, a.z + c.z, a.w + c.w);
    }
  }
  {
    const int c  = tid & 31;
    const int j0 = (tid >> 5) << 5;
    const float* p = E2 + base + i0 + c;
#pragma unroll
    for (int jj = 0; jj < 32; ++jj)
      ST[j0 + jj][c] = p[(size_t)(j0 + jj) << 8];
  }
  __syncthreads();

  const int r  = tid >> 3;
  const int t7 = tid & 7;
  float z[32];
  float m = -3.4e38f;
#pragma unroll
  for (int k = 0; k < 32; ++k) {
    const int j = t7 + (k << 3);
    const float e = SR[r][j] + ST[j][r];
    z[k] = -e;
    m = fmaxf(m, z[k]);
  }
  m = fmaxf(m, __shfl_xor(m, 1, 64));
  m = fmaxf(m, __shfl_xor(m, 2, 64));
  m = fmaxf(m, __shfl_xor(m, 4, 64));
  float ssum = 0.f;
#pragma unroll
  for (int k = 0; k < 32; ++k) { z[k] = expf(z[k] - m); ssum += z[k]; }
  ssum += __shfl_xor(ssum, 1, 64);
  ssum += __shfl_xor(ssum, 2, 64);
  ssum += __shfl_xor(ssum, 4, 64);
  const float inv = 1.f / ssum;

  unsigned short* arow = (unsigned short*)att + base + ((size_t)(i0 + r) << 8);
#pragma unroll
  for (int k = 0; k < 32; ++k) {
    const int j = t7 + (k << 3);
    arow[j] = (unsigned short)f2bf(z[k] * inv);
  }
}

// ---------------------------------------------------------------------------
// Kernel 3 (REWRITTEN): out = gamma * (att @ x) + x
// Tile 128(M=i) x 128(N=t), FULL K = 256 resident in LDS.
// A = att tile [i][j] 64 KiB bf16; B = x tile transposed [t][j] 64 KiB bf16.
// Stage everything -> ONE barrier -> 8 k-steps of pure ds_read+MFMA
// (zero in-loop barriers). Granule-XOR swizzle (g ^= row&7) makes the
// 64 ds_read_b128 per thread conflict-free; the 16 staging ds_writes
// eat the conflicts instead (negligible).
// Grid = 32 b * 2 it * 32 tt = 2048 blocks, 256 thr (4 waves, 2x2, 64x64/wave).
// ---------------------------------------------------------------------------
__global__ __launch_bounds__(256, 1)
void pv_kernel(const float* __restrict__ x, const __hip_bfloat16* __restrict__ att,
               const float* __restrict__ gamma, float* __restrict__ out) {
  __shared__ __align__(16) short As[128 * 256];   // 64 KiB: rows i, k=j contig
  __shared__ __align__(16) short Bs[128 * 256];   // 64 KiB: rows t, k=j contig

  const int tid = threadIdx.x;
  const int bx  = blockIdx.x;
  const int b   = bx >> 6;
  const int i0  = ((bx >> 5) & 1) << 7;  // 0 / 128
  const int t0  = (bx & 31) << 7;        // t-tile * 128

  const float* xb = x + ((size_t)b << 20) + t0;
  const unsigned short* attb =
      (const unsigned short*)att + ((size_t)b << 16) + ((size_t)i0 << 8);

  // ---- stage A: 4096 granules (16 B each), linear LDS, pre-swizzled source.
  // position p = c*256 + tid: row = p>>5, lds granule = p&31,
  // source granule = (p&31) ^ (row&7)   => LDS[r][g] = att[r][g ^ (r&7)]
  {
    uint4 areg[16];
#pragma unroll
    for (int c = 0; c < 16; ++c) {
      const int p = (c << 8) + tid;
      const int r = p >> 5;
      const int g = (p & 31) ^ (r & 7);
      areg[c] = *(const uint4*)(attb + (r << 8) + (g << 3));
    }
#pragma unroll
    for (int c = 0; c < 16; ++c) {
      const int p = (c << 8) + tid;
      *(uint4*)((char*)As + ((size_t)p << 4)) = areg[c];
    }
  }

  // ---- stage B: thread (tQ = tid&31, jg = tid>>5) covers t-quad 4*tQ..+3,
  // j-range 32*jg..+31, in 4 chunks of 8 j. Loads are float4 along t
  // (coalesced 512 B per half-wave); writes are swizzled granules.
  {
    const int tQ = tid & 31;
    const int jg = tid >> 5;
#pragma unroll
    for (int j8 = 0; j8 < 4; ++j8) {
      floatx4 v[8];
#pragma unroll
      for (int u = 0; u < 8; ++u) {
        const int j = (jg << 5) + (j8 << 3) + u;
        v[u] = *(const floatx4*)(xb + (size_t)j * TDIM + (tQ << 2));
      }
#pragma unroll
      for (int tt = 0; tt < 4; ++tt) {
        uint4 wv = make_uint4(cvt_pk_bf16(v[0][tt], v[1][tt]),
                              cvt_pk_bf16(v[2][tt], v[3][tt]),
                              cvt_pk_bf16(v[4][tt], v[5][tt]),
                              cvt_pk_bf16(v[6][tt], v[7][tt]));
        const int row = (tQ << 2) + tt;
        const int g   = ((jg << 2) + j8) ^ (row & 7);
        *(uint4*)((char*)Bs + (size_t)row * 512 + ((size_t)g << 4)) = wv;
      }
    }
  }

  floatx4 acc[4][4];
#pragma unroll
  for (int m = 0; m < 4; ++m)
#pragma unroll
    for (int n = 0; n < 4; ++n) acc[m][n] = {0.f, 0.f, 0.f, 0.f};

  const int lane = tid & 63;
  const int w    = tid >> 6;
  const int wm   = (w >> 1) << 6;  // 0 / 64
  const int wn   = (w & 1) << 6;
  const int fr   = lane & 15;
  const int q    = lane >> 4;

  __syncthreads();

  // ---- K-loop: fully resident, no barriers. 8 k-steps of 32 j each.
#pragma unroll
  for (int ks = 0; ks < 8; ++ks) {
    short8 Af[4], Bf[4];
#pragma unroll
    for (int m = 0; m < 4; ++m) {
      const int r = wm + 16 * m + fr;
      const int g = ((ks << 2) + q) ^ (r & 7);
      Af[m] = *(const short8*)((char*)As + (size_t)r * 512 + ((size_t)g << 4));
    }
#pragma unroll
    for (int n = 0; n < 4; ++n) {
      const int r = wn + 16 * n + fr;
      const int g = ((ks << 2) + q) ^ (r & 7);
      Bf[n] = *(const short8*)((char*)Bs + (size_t)r * 512 + ((size_t)g << 4));
    }
#pragma unroll
    for (int m = 0; m < 4; ++m)
#pragma unroll
      for (int n = 0; n < 4; ++n)
        acc[m][n] = __builtin_amdgcn_mfma_f32_16x16x32_bf16(Af[m], Bf[n], acc[m][n], 0, 0, 0);
  }

  const float g = gamma[0];
#pragma unroll
  for (int m = 0; m < 4; ++m)
#pragma unroll
    for (int n = 0; n < 4; ++n) {
      const int gr = i0 + wm + 16 * m + 4 * q;
      const int gc = t0 + wn + 16 * n + fr;
      size_t base = ((size_t)b << 20) + (size_t)gr * TDIM + gc;
#pragma unroll
      for (int r = 0; r < 4; ++r) {
        size_t idx = base + (size_t)r * TDIM;
        out[idx] = g * acc[m][n][r] + x[idx];
      }
    }
}

// ---------------------------------------------------------------------------
extern "C" void kernel_launch(void* const* d_in, const int* in_sizes, int n_in,
                              void* d_out, int out_size, void* d_ws, size_t ws_size,
                              hipStream_t stream) {
  (void)in_sizes; (void)n_in; (void)out_size; (void)ws_size;
  const float* x     = (const float*)d_in[0];
  const float* gamma = (const float*)d_in[1];
  float* out = (float*)d_out;

  const size_t EN = (size_t)BATCH * CDIM * CDIM;  // 2,097,152
  float* E1 = (float*)d_ws;
  float* E2 = E1 + EN;
  __hip_bfloat16* att = (__hip_bfloat16*)(E2 + EN);
  // ws usage: 8 MiB + 8 MiB + 4 MiB = 20 MiB (unchanged)

  gram_kernel<<<dim3(256), dim3(512), 0, stream>>>(x, E1, E2);
  softmax_kernel<<<dim3(BATCH * 8), dim3(256), 0, stream>>>(E1, E2, att);
  pv_kernel<<<dim3(2048), dim3(256), 0, stream>>>(x, att, gamma, out);
}

// Round 3
// 371.301 us; speedup vs baseline: 1.1142x; 1.0773x over previous
//
#include <hip/hip_runtime.h>
#include <hip/hip_bf16.h>

#define BATCH 32
#define CDIM  256
#define TDIM  4096

using short8  = __attribute__((ext_vector_type(8))) short;
using floatx4 = __attribute__((ext_vector_type(4))) float;
typedef unsigned short u16;

// RNE float -> bf16 (finite inputs)
__device__ __forceinline__ unsigned f2bf(float f) {
  unsigned u = __float_as_uint(f);
  return (u + 0x7fffu + ((u >> 16) & 1u)) >> 16;
}
__device__ __forceinline__ unsigned cvt_pk_bf16(float a, float b) {
  return f2bf(a) | (f2bf(b) << 16);
}
__device__ __forceinline__ float bf_lo(unsigned u) { return __uint_as_float(u << 16); }
__device__ __forceinline__ float bf_hi(unsigned u) { return __uint_as_float(u & 0xffff0000u); }

// async global->LDS, 16B per lane; LDS dest must be wave-uniform base.
__device__ __forceinline__ void glds16(const void* g, void* l) {
  __builtin_amdgcn_global_load_lds(
      (const __attribute__((address_space(1))) void*)g,
      (__attribute__((address_space(3))) void*)l, 16, 0, 0);
}

// ---------------------------------------------------------------------------
// Kernel 0: split prepass.  hx = bf16(x), lx = bf16(x - hx).
// Pure streaming: 128 MiB in, 128 MiB out. grid 2048 x 256, 8 groups/thread.
// ---------------------------------------------------------------------------
__global__ __launch_bounds__(256)
void split_kernel(const float* __restrict__ x, u16* __restrict__ hx,
                  u16* __restrict__ lx) {
  const unsigned gid0 = blockIdx.x * 256 + threadIdx.x;
#pragma unroll
  for (int it = 0; it < 8; ++it) {
    const size_t g8 = ((size_t)gid0 + (size_t)it * (2048u * 256u)) * 8;
    const float4 a = *(const float4*)(x + g8);
    const float4 c = *(const float4*)(x + g8 + 4);
    unsigned h0 = cvt_pk_bf16(a.x, a.y), h1 = cvt_pk_bf16(a.z, a.w);
    unsigned h2 = cvt_pk_bf16(c.x, c.y), h3 = cvt_pk_bf16(c.z, c.w);
    unsigned l0 = cvt_pk_bf16(a.x - bf_lo(h0), a.y - bf_hi(h0));
    unsigned l1 = cvt_pk_bf16(a.z - bf_lo(h1), a.w - bf_hi(h1));
    unsigned l2 = cvt_pk_bf16(c.x - bf_lo(h2), c.y - bf_hi(h2));
    unsigned l3 = cvt_pk_bf16(c.z - bf_lo(h3), c.w - bf_hi(h3));
    *(uint4*)(hx + g8) = make_uint4(h0, h1, h2, h3);
    *(uint4*)(lx + g8) = make_uint4(l0, l1, l2, l3);
  }
}

// ---------------------------------------------------------------------------
// Kernel 1: Gram as pure bf16 GEMM from hx/lx.
//   S = (h h^T + l h^T), E2 = l h^T   (energy[i,j] = S[i,j] + E2[j,i])
// Tile 128(I) x 64(J), BK = 64, grid 256, 512 thr (8 waves, 4x2, 32x32/wave).
// Staging: direct global_load_lds dwordx4, double-buffered (2 x 40 KiB LDS).
// Swizzle: LDS[r][g16] = src[r][g16 ^ (r&7)] via pre-swizzled SOURCE address
// (linear glds dest), swizzled ds_read (identical read math to prev round).
// ---------------------------------------------------------------------------
__global__ __launch_bounds__(512, 1)
void gram_gemm(const u16* __restrict__ hx, const u16* __restrict__ lx,
               float* __restrict__ S, float* __restrict__ E2) {
  // per buffer: hI 128x64 | lI 128x64 | hJ 64x64 shorts = 20480 shorts (40 KiB)
  __shared__ __align__(16) short lds[2 * 20480];

  const int tid = threadIdx.x;
  const int bx  = blockIdx.x;

  // XCD swizzle: one batch's 8 tile-jobs land on one XCD.
  const int s8  = bx & 7;
  const int seq = bx >> 3;
  const int b   = s8 + ((seq >> 3) << 3);
  const int job = seq & 7;
  const int i0  = (job >> 2) << 7;   // 0 / 128
  const int j0  = (job & 3) << 6;    // 0 / 64 / 128 / 192

  const int lane = tid & 63;
  const int w    = tid >> 6;         // 0..7

  // ---- staging: 40 chunks of 1 KiB (8 rows x 128 B); wave w owns chunk
  // c = s*8 + w for slot s = 0..4.  flat rows: [0,128) hI, [128,256) lI,
  // [256,320) hJ.  For every slot, row&7 == lane>>3.
  const int rsub = lane >> 3;                    // row within chunk
  const int gsw  = ((lane & 7) ^ rsub) << 3;     // pre-swizzled src granule (shorts)
  const size_t xb = (size_t)b << 20;
  const u16* src[5];
  src[0] = hx + xb + (size_t)(i0 +      w * 8 + rsub) * TDIM + gsw;
  src[1] = hx + xb + (size_t)(i0 + 64 + w * 8 + rsub) * TDIM + gsw;
  src[2] = lx + xb + (size_t)(i0 +      w * 8 + rsub) * TDIM + gsw;
  src[3] = lx + xb + (size_t)(i0 + 64 + w * 8 + rsub) * TDIM + gsw;
  src[4] = hx + xb + (size_t)(j0 +      w * 8 + rsub) * TDIM + gsw;
  int dstoff[5];
#pragma unroll
  for (int s = 0; s < 5; ++s) dstoff[s] = (s * 8 + w) << 9;   // chunk*512 shorts

  floatx4 acc1[2][2], acc2[2][2];
#pragma unroll
  for (int m = 0; m < 2; ++m)
#pragma unroll
    for (int n = 0; n < 2; ++n) {
      acc1[m][n] = {0.f, 0.f, 0.f, 0.f};
      acc2[m][n] = {0.f, 0.f, 0.f, 0.f};
    }

  const int wib = (w >> 1) << 5;   // 0/32/64/96
  const int wjb = (w & 1) << 5;    // 0/32
  const int fr  = lane & 15;
  const int q   = lane >> 4;
  const int f7  = fr & 7;

  const int g0 = ((q)     ^ f7) << 3;
  const int g1 = ((q + 4) ^ f7) << 3;
  const int a0 = (wib + fr) << 6;
  const int a1 = a0 + (16 << 6);
  const int b0 = (wjb + fr) << 6;
  const int b1 = b0 + (16 << 6);

  // prologue: stage K-step 0 into buffer 0
#pragma unroll
  for (int s = 0; s < 5; ++s) glds16(src[s], lds + dstoff[s]);
  __syncthreads();

  for (int ks = 0; ks < 64; ++ks) {
    const int cur = ks & 1;
    if (ks < 63) {
      const int nb = (cur ^ 1) * 20480;
#pragma unroll
      for (int s = 0; s < 5; ++s)
        glds16(src[s] + ((ks + 1) << 6), lds + nb + dstoff[s]);
    }
    const int bb = cur * 20480;

    {
      short8 Ah0 = *(const short8*)&lds[bb + a0 + g0];
      short8 Ah1 = *(const short8*)&lds[bb + a1 + g0];
      short8 Al0 = *(const short8*)&lds[bb + 8192 + a0 + g0];
      short8 Al1 = *(const short8*)&lds[bb + 8192 + a1 + g0];
      short8 Bh0 = *(const short8*)&lds[bb + 16384 + b0 + g0];
      short8 Bh1 = *(const short8*)&lds[bb + 16384 + b1 + g0];
      acc1[0][0] = __builtin_amdgcn_mfma_f32_16x16x32_bf16(Ah0, Bh0, acc1[0][0], 0, 0, 0);
      acc1[0][1] = __builtin_amdgcn_mfma_f32_16x16x32_bf16(Ah0, Bh1, acc1[0][1], 0, 0, 0);
      acc1[1][0] = __builtin_amdgcn_mfma_f32_16x16x32_bf16(Ah1, Bh0, acc1[1][0], 0, 0, 0);
      acc1[1][1] = __builtin_amdgcn_mfma_f32_16x16x32_bf16(Ah1, Bh1, acc1[1][1], 0, 0, 0);
      acc2[0][0] = __builtin_amdgcn_mfma_f32_16x16x32_bf16(Al0, Bh0, acc2[0][0], 0, 0, 0);
      acc2[0][1] = __builtin_amdgcn_mfma_f32_16x16x32_bf16(Al0, Bh1, acc2[0][1], 0, 0, 0);
      acc2[1][0] = __builtin_amdgcn_mfma_f32_16x16x32_bf16(Al1, Bh0, acc2[1][0], 0, 0, 0);
      acc2[1][1] = __builtin_amdgcn_mfma_f32_16x16x32_bf16(Al1, Bh1, acc2[1][1], 0, 0, 0);
    }
    {
      short8 Ah0 = *(const short8*)&lds[bb + a0 + g1];
      short8 Ah1 = *(const short8*)&lds[bb + a1 + g1];
      short8 Al0 = *(const short8*)&lds[bb + 8192 + a0 + g1];
      short8 Al1 = *(const short8*)&lds[bb + 8192 + a1 + g1];
      short8 Bh0 = *(const short8*)&lds[bb + 16384 + b0 + g1];
      short8 Bh1 = *(const short8*)&lds[bb + 16384 + b1 + g1];
      acc1[0][0] = __builtin_amdgcn_mfma_f32_16x16x32_bf16(Ah0, Bh0, acc1[0][0], 0, 0, 0);
      acc1[0][1] = __builtin_amdgcn_mfma_f32_16x16x32_bf16(Ah0, Bh1, acc1[0][1], 0, 0, 0);
      acc1[1][0] = __builtin_amdgcn_mfma_f32_16x16x32_bf16(Ah1, Bh0, acc1[1][0], 0, 0, 0);
      acc1[1][1] = __builtin_amdgcn_mfma_f32_16x16x32_bf16(Ah1, Bh1, acc1[1][1], 0, 0, 0);
      acc2[0][0] = __builtin_amdgcn_mfma_f32_16x16x32_bf16(Al0, Bh0, acc2[0][0], 0, 0, 0);
      acc2[0][1] = __builtin_amdgcn_mfma_f32_16x16x32_bf16(Al0, Bh1, acc2[0][1], 0, 0, 0);
      acc2[1][0] = __builtin_amdgcn_mfma_f32_16x16x32_bf16(Al1, Bh0, acc2[1][0], 0, 0, 0);
      acc2[1][1] = __builtin_amdgcn_mfma_f32_16x16x32_bf16(Al1, Bh1, acc2[1][1], 0, 0, 0);
    }
    __syncthreads();   // drains this iter's glds; next iter's buffer ready
  }

  // epilogue: S = acc1 + acc2, E2 = acc2.  C/D: col = lane&15, row = q*4 + r
#pragma unroll
  for (int m = 0; m < 2; ++m)
#pragma unroll
    for (int n = 0; n < 2; ++n) {
      const int gr = i0 + wib + 16 * m + 4 * q;
      const int gc = j0 + wjb + 16 * n + fr;
      size_t base = (((size_t)b * CDIM + gr) << 8) + gc;
#pragma unroll
      for (int r = 0; r < 4; ++r) {
        S[base + ((size_t)r << 8)]  = acc1[m][n][r] + acc2[m][n][r];
        E2[base + ((size_t)r << 8)] = acc2[m][n][r];
      }
    }
}

// ---------------------------------------------------------------------------
// Kernel 1-fallback: fused fp32 gram (prev round), S-epilogue. Used only if
// ws_size can't hold hx/lx.
// ---------------------------------------------------------------------------
__global__ __launch_bounds__(512, 1)
void gram_fused(const float* __restrict__ x,
                float* __restrict__ S, float* __restrict__ E2) {
  __shared__ __align__(16) short hI[128 * 64];
  __shared__ __align__(16) short lI[128 * 64];
  __shared__ __align__(16) short hJ[64 * 64];

  const int tid = threadIdx.x;
  const int bx  = blockIdx.x;
  const int s   = bx & 7;
  const int seq = bx >> 3;
  const int b   = s + ((seq >> 3) << 3);
  const int job = seq & 7;
  const int i0  = (job >> 2) << 7;
  const int j0  = (job & 3) << 6;

  const float* xb = x + ((size_t)b << 20);

  const bool isJ   = tid >= 256;
  const int  irow  = tid >> 1;
  const int  ihalf = tid & 1;
  const int  jrow  = (tid & 255) >> 2;
  const int  jq    = tid & 3;

  const float* pS = isJ
      ? xb + (size_t)(j0 + jrow) * TDIM + (jq << 4)
      : xb + (size_t)(i0 + irow) * TDIM + (ihalf << 5);

  floatx4 acc1[2][2], acc2[2][2];
#pragma unroll
  for (int m = 0; m < 2; ++m)
#pragma unroll
    for (int n = 0; n < 2; ++n) {
      acc1[m][n] = {0.f, 0.f, 0.f, 0.f};
      acc2[m][n] = {0.f, 0.f, 0.f, 0.f};
    }

  const int lane = tid & 63;
  const int w    = tid >> 6;
  const int wib  = (w >> 1) << 5;
  const int wjb  = (w & 1) << 5;
  const int fr   = lane & 15;
  const int q    = lane >> 4;
  const int f7   = fr & 7;

  const int g0 = ((q)     ^ f7) << 3;
  const int g1 = ((q + 4) ^ f7) << 3;
  const int a0 = (wib + fr) << 6;
  const int a1 = a0 + (16 << 6);
  const int b0 = (wjb + fr) << 6;
  const int b1 = b0 + (16 << 6);

  float4 r0, r1, r2, r3, r4, r5, r6, r7;
  r0 = ((const float4*)pS)[0]; r1 = ((const float4*)pS)[1];
  r2 = ((const float4*)pS)[2]; r3 = ((const float4*)pS)[3];
  if (!isJ) {
    r4 = ((const float4*)pS)[4]; r5 = ((const float4*)pS)[5];
    r6 = ((const float4*)pS)[6]; r7 = ((const float4*)pS)[7];
  }

  for (int ks = 0; ks < TDIM / 64; ++ks) {
    unsigned h0 = cvt_pk_bf16(r0.x, r0.y), h1 = cvt_pk_bf16(r0.z, r0.w);
    unsigned h2 = cvt_pk_bf16(r1.x, r1.y), h3 = cvt_pk_bf16(r1.z, r1.w);
    unsigned h4 = cvt_pk_bf16(r2.x, r2.y), h5 = cvt_pk_bf16(r2.z, r2.w);
    unsigned h6 = cvt_pk_bf16(r3.x, r3.y), h7 = cvt_pk_bf16(r3.z, r3.w);
    unsigned h8, h9, hA, hB, hC, hD, hE, hF;
    unsigned l0, l1, l2, l3, l4, l5, l6, l7, l8, l9, lA, lB, lC, lD, lE, lF;
    if (!isJ) {
      h8 = cvt_pk_bf16(r4.x, r4.y); h9 = cvt_pk_bf16(r4.z, r4.w);
      hA = cvt_pk_bf16(r5.x, r5.y); hB = cvt_pk_bf16(r5.z, r5.w);
      hC = cvt_pk_bf16(r6.x, r6.y); hD = cvt_pk_bf16(r6.z, r6.w);
      hE = cvt_pk_bf16(r7.x, r7.y); hF = cvt_pk_bf16(r7.z, r7.w);
      l0 = cvt_pk_bf16(r0.x - bf_lo(h0), r0.y - bf_hi(h0));
      l1 = cvt_pk_bf16(r0.z - bf_lo(h1), r0.w - bf_hi(h1));
      l2 = cvt_pk_bf16(r1.x - bf_lo(h2), r1.y - bf_hi(h2));
      l3 = cvt_pk_bf16(r1.z - bf_lo(h3), r1.w - bf_hi(h3));
      l4 = cvt_pk_bf16(r2.x - bf_lo(h4), r2.y - bf_hi(h4));
      l5 = cvt_pk_bf16(r2.z - bf_lo(h5), r2.w - bf_hi(h5));
      l6 = cvt_pk_bf16(r3.x - bf_lo(h6), r3.y - bf_hi(h6));
      l7 = cvt_pk_bf16(r3.z - bf_lo(h7), r3.w - bf_hi(h7));
      l8 = cvt_pk_bf16(r4.x - bf_lo(h8), r4.y - bf_hi(h8));
      l9 = cvt_pk_bf16(r4.z - bf_lo(h9), r4.w - bf_hi(h9));
      lA = cvt_pk_bf16(r5.x - bf_lo(hA), r5.y - bf_hi(hA));
      lB = cvt_pk_bf16(r5.z - bf_lo(hB), r5.w - bf_hi(hB));
      lC = cvt_pk_bf16(r6.x - bf_lo(hC), r6.y - bf_hi(hC));
      lD = cvt_pk_bf16(r6.z - bf_lo(hD), r6.w - bf_hi(hD));
      lE = cvt_pk_bf16(r7.x - bf_lo(hE), r7.y - bf_hi(hE));
      lF = cvt_pk_bf16(r7.z - bf_lo(hF), r7.w - bf_hi(hF));
    }

    __syncthreads();
    if (!isJ) {
      const int rb = irow << 6;
      const int s7 = irow & 7;
      const int gb = ihalf << 2;
      *(uint4*)&hI[rb + (((gb + 0) ^ s7) << 3)] = make_uint4(h0, h1, h2, h3);
      *(uint4*)&hI[rb + (((gb + 1) ^ s7) << 3)] = make_uint4(h4, h5, h6, h7);
      *(uint4*)&hI[rb + (((gb + 2) ^ s7) << 3)] = make_uint4(h8, h9, hA, hB);
      *(uint4*)&hI[rb + (((gb + 3) ^ s7) << 3)] = make_uint4(hC, hD, hE, hF);
      *(uint4*)&lI[rb + (((gb + 0) ^ s7) << 3)] = make_uint4(l0, l1, l2, l3);
      *(uint4*)&lI[rb + (((gb + 1) ^ s7) << 3)] = make_uint4(l4, l5, l6, l7);
      *(uint4*)&lI[rb + (((gb + 2) ^ s7) << 3)] = make_uint4(l8, l9, lA, lB);
      *(uint4*)&lI[rb + (((gb + 3) ^ s7) << 3)] = make_uint4(lC, lD, lE, lF);
    } else {
      const int rb = jrow << 6;
      const int s7 = jrow & 7;
      const int gb = jq << 1;
      *(uint4*)&hJ[rb + (((gb + 0) ^ s7) << 3)] = make_uint4(h0, h1, h2, h3);
      *(uint4*)&hJ[rb + (((gb + 1) ^ s7) << 3)] = make_uint4(h4, h5, h6, h7);
    }
    __syncthreads();

    if (ks < TDIM / 64 - 1) {
      pS += 64;
      r0 = ((const float4*)pS)[0]; r1 = ((const float4*)pS)[1];
      r2 = ((const float4*)pS)[2]; r3 = ((const float4*)pS)[3];
      if (!isJ) {
        r4 = ((const float4*)pS)[4]; r5 = ((const float4*)pS)[5];
        r6 = ((const float4*)pS)[6]; r7 = ((const float4*)pS)[7];
      }
    }

    {
      short8 Ah0 = *(const short8*)&hI[a0 + g0];
      short8 Ah1 = *(const short8*)&hI[a1 + g0];
      short8 Al0 = *(const short8*)&lI[a0 + g0];
      short8 Al1 = *(const short8*)&lI[a1 + g0];
      short8 Bh0 = *(const short8*)&hJ[b0 + g0];
      short8 Bh1 = *(const short8*)&hJ[b1 + g0];
      acc1[0][0] = __builtin_amdgcn_mfma_f32_16x16x32_bf16(Ah0, Bh0, acc1[0][0], 0, 0, 0);
      acc1[0][1] = __builtin_amdgcn_mfma_f32_16x16x32_bf16(Ah0, Bh1, acc1[0][1], 0, 0, 0);
      acc1[1][0] = __builtin_amdgcn_mfma_f32_16x16x32_bf16(Ah1, Bh0, acc1[1][0], 0, 0, 0);
      acc1[1][1] = __builtin_amdgcn_mfma_f32_16x16x32_bf16(Ah1, Bh1, acc1[1][1], 0, 0, 0);
      acc2[0][0] = __builtin_amdgcn_mfma_f32_16x16x32_bf16(Al0, Bh0, acc2[0][0], 0, 0, 0);
      acc2[0][1] = __builtin_amdgcn_mfma_f32_16x16x32_bf16(Al0, Bh1, acc2[0][1], 0, 0, 0);
      acc2[1][0] = __builtin_amdgcn_mfma_f32_16x16x32_bf16(Al1, Bh0, acc2[1][0], 0, 0, 0);
      acc2[1][1] = __builtin_amdgcn_mfma_f32_16x16x32_bf16(Al1, Bh1, acc2[1][1], 0, 0, 0);
    }
    {
      short8 Ah0 = *(const short8*)&hI[a0 + g1];
      short8 Ah1 = *(const short8*)&hI[a1 + g1];
      short8 Al0 = *(const short8*)&lI[a0 + g1];
      short8 Al1 = *(const short8*)&lI[a1 + g1];
      short8 Bh0 = *(const short8*)&hJ[b0 + g1];
      short8 Bh1 = *(const short8*)&hJ[b1 + g1];
      acc1[0][0] = __builtin_amdgcn_mfma_f32_16x16x32_bf16(Ah0, Bh0, acc1[0][0], 0, 0, 0);
      acc1[0][1] = __builtin_amdgcn_mfma_f32_16x16x32_bf16(Ah0, Bh1, acc1[0][1], 0, 0, 0);
      acc1[1][0] = __builtin_amdgcn_mfma_f32_16x16x32_bf16(Ah1, Bh0, acc1[1][0], 0, 0, 0);
      acc1[1][1] = __builtin_amdgcn_mfma_f32_16x16x32_bf16(Ah1, Bh1, acc1[1][1], 0, 0, 0);
      acc2[0][0] = __builtin_amdgcn_mfma_f32_16x16x32_bf16(Al0, Bh0, acc2[0][0], 0, 0, 0);
      acc2[0][1] = __builtin_amdgcn_mfma_f32_16x16x32_bf16(Al0, Bh1, acc2[0][1], 0, 0, 0);
      acc2[1][0] = __builtin_amdgcn_mfma_f32_16x16x32_bf16(Al1, Bh0, acc2[1][0], 0, 0, 0);
      acc2[1][1] = __builtin_amdgcn_mfma_f32_16x16x32_bf16(Al1, Bh1, acc2[1][1], 0, 0, 0);
    }
  }

#pragma unroll
  for (int m = 0; m < 2; ++m)
#pragma unroll
    for (int n = 0; n < 2; ++n) {
      const int gr = i0 + wib + 16 * m + 4 * q;
      const int gc = j0 + wjb + 16 * n + fr;
      size_t base = (((size_t)b * CDIM + gr) << 8) + gc;
#pragma unroll
      for (int r = 0; r < 4; ++r) {
        S[base + ((size_t)r << 8)]  = acc1[m][n][r] + acc2[m][n][r];
        E2[base + ((size_t)r << 8)] = acc2[m][n][r];
      }
    }
}

// ---------------------------------------------------------------------------
// Kernel 2: softmax over rows of energy = S + E2^T, att = softmax(-energy)
// ---------------------------------------------------------------------------
__global__ __launch_bounds__(256)
void softmax_kernel(const float* __restrict__ S, const float* __restrict__ E2,
                    __hip_bfloat16* __restrict__ att) {
  __shared__ float SR[32][264];
  __shared__ float ST[256][33];

  const int tid = threadIdx.x;
  const int b   = blockIdx.x >> 3;
  const int i0  = (blockIdx.x & 7) << 5;
  const size_t base = (size_t)b << 16;

  {
    const int r  = tid >> 3;
    const int c0 = (tid & 7) << 5;
    const float* p1 = S + base + ((size_t)(i0 + r) << 8) + c0;
#pragma unroll
    for (int u = 0; u < 32; u += 4)
      *(float4*)&SR[r][c0 + u] = *(const float4*)(p1 + u);
  }
  {
    const int c  = tid & 31;
    const int j0 = (tid >> 5) << 5;
    const float* p = E2 + base + i0 + c;
#pragma unroll
    for (int jj = 0; jj < 32; ++jj)
      ST[j0 + jj][c] = p[(size_t)(j0 + jj) << 8];
  }
  __syncthreads();

  const int r  = tid >> 3;
  const int t7 = tid & 7;
  float z[32];
  float m = -3.4e38f;
#pragma unroll
  for (int k = 0; k < 32; ++k) {
    const int j = t7 + (k << 3);
    const float e = SR[r][j] + ST[j][r];
    z[k] = -e;
    m = fmaxf(m, z[k]);
  }
  m = fmaxf(m, __shfl_xor(m, 1, 64));
  m = fmaxf(m, __shfl_xor(m, 2, 64));
  m = fmaxf(m, __shfl_xor(m, 4, 64));
  float ssum = 0.f;
#pragma unroll
  for (int k = 0; k < 32; ++k) { z[k] = expf(z[k] - m); ssum += z[k]; }
  ssum += __shfl_xor(ssum, 1, 64);
  ssum += __shfl_xor(ssum, 2, 64);
  ssum += __shfl_xor(ssum, 4, 64);
  const float inv = 1.f / ssum;

  u16* arow = (u16*)att + base + ((size_t)(i0 + r) << 8);
#pragma unroll
  for (int k = 0; k < 32; ++k) {
    const int j = t7 + (k << 3);
    arow[j] = (u16)f2bf(z[k] * inv);
  }
}

// ---------------------------------------------------------------------------
// Kernel 3: out = gamma * (att @ x) + x.  Full K = 256 resident.
// A (att) staged via direct global_load_lds (pre-swizzled source);
// B staged from hx (bf16, half the bytes of x) with 16-bit repack.
// T14 order: B reg-loads issued first, A glds second, repack last.
// ---------------------------------------------------------------------------
__global__ __launch_bounds__(256, 1)
void pv_kernel(const float* __restrict__ x, const u16* __restrict__ hx,
               const __hip_bfloat16* __restrict__ att,
               const float* __restrict__ gamma, float* __restrict__ out) {
  __shared__ __align__(16) short As[128 * 256];   // rows i, k=j contig
  __shared__ __align__(16) short Bs[128 * 256];   // rows t, k=j contig

  const int tid = threadIdx.x;
  const int bx  = blockIdx.x;
  const int b   = bx >> 6;
  const int i0  = ((bx >> 5) & 1) << 7;
  const int t0  = (bx & 31) << 7;

  const u16* attb = (const u16*)att + ((size_t)b << 16) + ((size_t)i0 << 8);
  const int lane = tid & 63;
  const int w4   = tid >> 6;   // wave 0..3

  // ---- B loads first (hx[j][t-quad], 8 B per load, 32 loads)
  const int tQ = tid & 31;
  const int jg = tid >> 5;     // 0..7
  const u16* hb = hx + ((size_t)b << 20) + t0 + (tQ << 2);
  uint2 v[4][8];
#pragma unroll
  for (int j8 = 0; j8 < 4; ++j8)
#pragma unroll
    for (int u = 0; u < 8; ++u)
      v[j8][u] = *(const uint2*)(hb + (size_t)((jg << 5) + (j8 << 3) + u) * TDIM);

  // ---- A stage: 64 chunks (2 rows each); wave w4 owns chunk c = s*4 + w4
#pragma unroll
  for (int s = 0; s < 16; ++s) {
    const int c  = (s << 2) + w4;
    const int r  = (c << 1) + (lane >> 5);
    const int gd = lane & 31;
    const int gs = gd ^ (r & 7);
    glds16(attb + ((size_t)r << 8) + (gs << 3), As + (c << 9));
  }

  // ---- B repack (extract 16-bit lane tt from uint2 pairs) + swizzled write
#pragma unroll
  for (int j8 = 0; j8 < 4; ++j8) {
#pragma unroll
    for (int tt = 0; tt < 4; ++tt) {
      unsigned p[4];
#pragma unroll
      for (int a = 0; a < 4; ++a) {
        const unsigned xa = (tt & 2) ? v[j8][2 * a].y : v[j8][2 * a].x;
        const unsigned xb2 = (tt & 2) ? v[j8][2 * a + 1].y : v[j8][2 * a + 1].x;
        p[a] = (tt & 1) ? ((xa >> 16) | (xb2 & 0xffff0000u))
                        : ((xa & 0xffffu) | (xb2 << 16));
      }
      const int row = (tQ << 2) + tt;
      const int g   = ((jg << 2) + j8) ^ (row & 7);
      *(uint4*)(Bs + row * 256 + (g << 3)) = make_uint4(p[0], p[1], p[2], p[3]);
    }
  }

  floatx4 acc[4][4];
#pragma unroll
  for (int m = 0; m < 4; ++m)
#pragma unroll
    for (int n = 0; n < 4; ++n) acc[m][n] = {0.f, 0.f, 0.f, 0.f};

  const int wm = (w4 >> 1) << 6;
  const int wn = (w4 & 1) << 6;
  const int fr = lane & 15;
  const int q  = lane >> 4;

  __syncthreads();   // drains A glds + B writes

  // ---- K-loop: fully resident, no barriers
#pragma unroll
  for (int ks = 0; ks < 8; ++ks) {
    short8 Af[4], Bf[4];
#pragma unroll
    for (int m = 0; m < 4; ++m) {
      const int r = wm + 16 * m + fr;
      const int g = ((ks << 2) + q) ^ (r & 7);
      Af[m] = *(const short8*)(As + r * 256 + (g << 3));
    }
#pragma unroll
    for (int n = 0; n < 4; ++n) {
      const int r = wn + 16 * n + fr;
      const int g = ((ks << 2) + q) ^ (r & 7);
      Bf[n] = *(const short8*)(Bs + r * 256 + (g << 3));
    }
#pragma unroll
    for (int m = 0; m < 4; ++m)
#pragma unroll
      for (int n = 0; n < 4; ++n)
        acc[m][n] = __builtin_amdgcn_mfma_f32_16x16x32_bf16(Af[m], Bf[n], acc[m][n], 0, 0, 0);
  }

  const float g = gamma[0];
#pragma unroll
  for (int m = 0; m < 4; ++m)
#pragma unroll
    for (int n = 0; n < 4; ++n) {
      const int gr = i0 + wm + 16 * m + 4 * q;
      const int gc = t0 + wn + 16 * n + fr;
      size_t base = ((size_t)b << 20) + (size_t)gr * TDIM + gc;
#pragma unroll
      for (int r = 0; r < 4; ++r) {
        size_t idx = base + (size_t)r * TDIM;
        out[idx] = g * acc[m][n][r] + x[idx];
      }
    }
}

// ---------------------------------------------------------------------------
// Kernel 3-fallback: prev-round pv reading x fp32 directly.
// ---------------------------------------------------------------------------
__global__ __launch_bounds__(256, 1)
void pv_fused(const float* __restrict__ x, const __hip_bfloat16* __restrict__ att,
              const float* __restrict__ gamma, float* __restrict__ out) {
  __shared__ __align__(16) short As[128 * 256];
  __shared__ __align__(16) short Bs[128 * 256];

  const int tid = threadIdx.x;
  const int bx  = blockIdx.x;
  const int b   = bx >> 6;
  const int i0  = ((bx >> 5) & 1) << 7;
  const int t0  = (bx & 31) << 7;

  const float* xb = x + ((size_t)b << 20) + t0;
  const u16* attb = (const u16*)att + ((size_t)b << 16) + ((size_t)i0 << 8);

  {
    uint4 areg[16];
#pragma unroll
    for (int c = 0; c < 16; ++c) {
      const int p = (c << 8) + tid;
      const int r = p >> 5;
      const int g = (p & 31) ^ (r & 7);
      areg[c] = *(const uint4*)(attb + (r << 8) + (g << 3));
    }
#pragma unroll
    for (int c = 0; c < 16; ++c) {
      const int p = (c << 8) + tid;
      *(uint4*)((char*)As + ((size_t)p << 4)) = areg[c];
    }
  }
  {
    const int tQ = tid & 31;
    const int jg = tid >> 5;
#pragma unroll
    for (int j8 = 0; j8 < 4; ++j8) {
      floatx4 v[8];
#pragma unroll
      for (int u = 0; u < 8; ++u) {
        const int j = (jg << 5) + (j8 << 3) + u;
        v[u] = *(const floatx4*)(xb + (size_t)j * TDIM + (tQ << 2));
      }
#pragma unroll
      for (int tt = 0; tt < 4; ++tt) {
        uint4 wv = make_uint4(cvt_pk_bf16(v[0][tt], v[1][tt]),
                              cvt_pk_bf16(v[2][tt], v[3][tt]),
                              cvt_pk_bf16(v[4][tt], v[5][tt]),
                              cvt_pk_bf16(v[6][tt], v[7][tt]));
        const int row = (tQ << 2) + tt;
        const int g   = ((jg << 2) + j8) ^ (row & 7);
        *(uint4*)((char*)Bs + (size_t)row * 512 + ((size_t)g << 4)) = wv;
      }
    }
  }

  floatx4 acc[4][4];
#pragma unroll
  for (int m = 0; m < 4; ++m)
#pragma unroll
    for (int n = 0; n < 4; ++n) acc[m][n] = {0.f, 0.f, 0.f, 0.f};

  const int lane = tid & 63;
  const int w    = tid >> 6;
  const int wm   = (w >> 1) << 6;
  const int wn   = (w & 1) << 6;
  const int fr   = lane & 15;
  const int q    = lane >> 4;

  __syncthreads();

#pragma unroll
  for (int ks = 0; ks < 8; ++ks) {
    short8 Af[4], Bf[4];
#pragma unroll
    for (int m = 0; m < 4; ++m) {
      const int r = wm + 16 * m + fr;
      const int g = ((ks << 2) + q) ^ (r & 7);
      Af[m] = *(const short8*)((char*)As + (size_t)r * 512 + ((size_t)g << 4));
    }
#pragma unroll
    for (int n = 0; n < 4; ++n) {
      const int r = wn + 16 * n + fr;
      const int g = ((ks << 2) + q) ^ (r & 7);
      Bf[n] = *(const short8*)((char*)Bs + (size_t)r * 512 + ((size_t)g << 4));
    }
#pragma unroll
    for (int m = 0; m < 4; ++m)
#pragma unroll
      for (int n = 0; n < 4; ++n)
        acc[m][n] = __builtin_amdgcn_mfma_f32_16x16x32_bf16(Af[m], Bf[n], acc[m][n], 0, 0, 0);
  }

  const float g = gamma[0];
#pragma unroll
  for (int m = 0; m < 4; ++m)
#pragma unroll
    for (int n = 0; n < 4; ++n) {
      const int gr = i0 + wm + 16 * m + 4 * q;
      const int gc = t0 + wn + 16 * n + fr;
      size_t base = ((size_t)b << 20) + (size_t)gr * TDIM + gc;
#pragma unroll
      for (int r = 0; r < 4; ++r) {
        size_t idx = base + (size_t)r * TDIM;
        out[idx] = g * acc[m][n][r] + x[idx];
      }
    }
}

// ---------------------------------------------------------------------------
extern "C" void kernel_launch(void* const* d_in, const int* in_sizes, int n_in,
                              void* d_out, int out_size, void* d_ws, size_t ws_size,
                              hipStream_t stream) {
  (void)in_sizes; (void)n_in; (void)out_size;
  const float* x     = (const float*)d_in[0];
  const float* gamma = (const float*)d_in[1];
  float* out = (float*)d_out;

  const size_t EN = (size_t)BATCH * CDIM * CDIM;       // 2,097,152
  const size_t XN = (size_t)BATCH * CDIM * TDIM;       // 33,554,432
  float* S  = (float*)d_ws;                            // 8 MiB
  float* E2 = S + EN;                                  // 8 MiB
  __hip_bfloat16* att = (__hip_bfloat16*)(E2 + EN);    // 4 MiB
  u16* hx = (u16*)((char*)d_ws + 20u * 1024 * 1024);   // 64 MiB
  u16* lx = hx + XN;                                   // 64 MiB
  const size_t need = 20u * 1024 * 1024 + 2 * XN * sizeof(u16);  // 148 MiB

  if (ws_size >= need) {
    split_kernel<<<dim3(2048), dim3(256), 0, stream>>>(x, hx, lx);
    gram_gemm<<<dim3(256), dim3(512), 0, stream>>>(hx, lx, S, E2);
    softmax_kernel<<<dim3(BATCH * 8), dim3(256), 0, stream>>>(S, E2, att);
    pv_kernel<<<dim3(2048), dim3(256), 0, stream>>>(x, hx, att, gamma, out);
  } else {
    gram_fused<<<dim3(256), dim3(512), 0, stream>>>(x, S, E2);
    softmax_kernel<<<dim3(BATCH * 8), dim3(256), 0, stream>>>(S, E2, att);
    pv_fused<<<dim3(2048), dim3(256), 0, stream>>>(x, att, gamma, out);
  }
}